// Round 6
// baseline (559.423 us; speedup 1.0000x reference)
//
#include <hip/hip_runtime.h>
#include <stdint.h>
#include <stddef.h>

// ---------------------------------------------------------------------------
// EnhancedSpatialAttention, round 6 (MI355X / gfx950).
// Key change vs r5: amdgpu_waves_per_eu(2,2) on K2/K3 pins the register
// allocator at 2 waves/EU (VGPR budget 256) -> xf[32]/acc[8][2][2] stay in
// registers instead of spilling to scratch (r5: VGPR_Count=128 with 128 VGPR
// of A-fragments = forced spill, +128MiB hidden WRITE traffic).
// Also: bqkv biases staged to LDS once (no vmem ops polluting the counted
// vmcnt queue), redundant in-body lgkmcnt(0) removed.
// ---------------------------------------------------------------------------

typedef __attribute__((ext_vector_type(8))) short short8;    // 8 bf16
typedef __attribute__((ext_vector_type(4))) float f32x4;     // MFMA C/D frag

typedef __attribute__((address_space(3))) unsigned int as3_u32;
typedef __attribute__((address_space(1))) unsigned int as1_u32;

#define VMCNT8 asm volatile("s_waitcnt vmcnt(8)" ::: "memory")
#define VMCNT5 asm volatile("s_waitcnt vmcnt(5)" ::: "memory")
#define VMCNT4 asm volatile("s_waitcnt vmcnt(4)" ::: "memory")
#define VMCNT0 asm volatile("s_waitcnt vmcnt(0)" ::: "memory")
#define LGKM0  asm volatile("s_waitcnt lgkmcnt(0)" ::: "memory")
#define BARR() __builtin_amdgcn_s_barrier()
#define PRIO1  __builtin_amdgcn_s_setprio(1)
#define PRIO0  __builtin_amdgcn_s_setprio(0)

__device__ __forceinline__ unsigned short f2bf(float f) {
  unsigned u = __builtin_bit_cast(unsigned, f);
  u = (u + 0x7FFFu + ((u >> 16) & 1u)) >> 16;   // RNE
  return (unsigned short)u;
}

__device__ __forceinline__ f32x4 mfma16(short8 a, short8 b, f32x4 c) {
  return __builtin_amdgcn_mfma_f32_16x16x32_bf16(a, b, c, 0, 0, 0);
}

// 64-row x 64-col bf16 scratch, 128B row stride, 16B-unit XOR swizzle.
__device__ __forceinline__ short8 rd8s(const char* buf, int row, int unit) {
  return *(const short8*)(buf + row * 128 + ((unit ^ (row & 7)) * 16));
}
__device__ __forceinline__ void wr2s(char* buf, int row, int col, unsigned short v) {
  int slot = (col >> 3) ^ (row & 7);
  *(unsigned short*)(buf + row * 128 + slot * 16 + (col & 7) * 2) = v;
}
__device__ __forceinline__ void wr8s(char* buf, int row, int col, uint2 v) {
  int slot = (col >> 3) ^ (row & 7);
  *(uint2*)(buf + row * 128 + slot * 16 + (col & 7) * 2) = v;
}

// Stage one 16KB chunk: 4 x global_load_lds dwordx4 per thread, linear LDS.
__device__ __forceinline__ void stage16k(char* ldsbase, const char* gsrc, int w, int lane) {
#pragma unroll
  for (int j = 0; j < 4; ++j) {
    int off = j * 4096 + w * 1024;
    __builtin_amdgcn_global_load_lds((const as1_u32*)(gsrc + off + lane * 16),
                                     (as3_u32*)(ldsbase + off), 16, 0, 0);
  }
}

// ============================ prep =========================================
__global__ void prep_kernel(const float* __restrict__ wqkv_f,
                            const float* __restrict__ wo_f,
                            const float* __restrict__ rel,
                            unsigned short* __restrict__ wt,
                            float* __restrict__ bias2d) {
  int b = blockIdx.x, tid = threadIdx.x;
  if (b < 128) {
    unsigned short* dst = wt + (size_t)b * 8192;
#pragma unroll
    for (int t = 0; t < 4; ++t) {
      int u = t * 256 + tid;          // 16B unit 0..1023
      int row = u >> 4, us = u & 15;
      int kg = (us & 8) | ((us ^ row) & 7);
      const float* src;
      if (b < 96) {                   // QKV chunk: h, rg, kc
        int h = b / 12, i = b % 12;
        int rg = i >> 2, kc = i & 3;
        src = wqkv_f + (size_t)(rg * 512 + h * 64 + row) * 512 + kc * 128 + kg * 8;
      } else {                        // Wo chunk: kc, ng
        int cw = b - 96;
        int kc = cw >> 3, ng = cw & 7;
        src = wo_f + (size_t)(ng * 64 + row) * 512 + kc * 128 + kg * 8;
      }
      float4 a = *(const float4*)src;
      float4 c = *(const float4*)(src + 4);
      unsigned p0 = (unsigned)f2bf(a.x) | ((unsigned)f2bf(a.y) << 16);
      unsigned p1 = (unsigned)f2bf(a.z) | ((unsigned)f2bf(a.w) << 16);
      unsigned p2 = (unsigned)f2bf(c.x) | ((unsigned)f2bf(c.y) << 16);
      unsigned p3 = (unsigned)f2bf(c.z) | ((unsigned)f2bf(c.w) << 16);
      *(uint4*)(dst + u * 8) = make_uint4(p0, p1, p2, p3);
    }
  } else {
    int idx = (b - 128) * 256 + tid;  // 0..4095
    int m = idx >> 6, nn = idx & 63;
    float s = 0.f;
#pragma unroll
    for (int hh = 0; hh < 8; ++hh) s += rel[hh * 16384 + m * 128 + nn];
    bias2d[idx] = s * 0.125f;
  }
}

// ============================ K2: attn_qkv =================================
__global__ __launch_bounds__(256)
__attribute__((amdgpu_waves_per_eu(2, 2))) void attn_qkv(
    const float* __restrict__ x,        // [2048,64,512] f32
    const char* __restrict__ wq,        // 96 x 16KB QKV chunks
    const float* __restrict__ bqkv,     // [1536]
    const float* __restrict__ bias2d,   // [64,64]
    char* __restrict__ ctxg) {          // d_out as ctx scratch (bf16)
  extern __shared__ __attribute__((aligned(16))) char smem[];  // 79872 B
  char* WS = smem;                 // 3 x 16KB staging
  char* B0 = smem + 49152;         // Q, then P (8KB swizzled)
  char* B1 = smem + 57344;         // K, then ctx
  char* B2 = smem + 65536;         // V^T
  float* BQ = (float*)(smem + 73728);  // bqkv copy (6KB)

  const int n = blockIdx.x;
  const int tid = threadIdx.x;
  const int w = tid >> 6, lane = tid & 63;
  const int l15 = lane & 15, g = lane >> 4;
  const int wm = w >> 1, wn = w & 1;   // proj wave grid 2M x 2N
  const int mrow = w * 16 + g * 4;     // attn-phase C rows
  const int wrow = w * 16 + l15;       // attn-phase A row

  // ---- bqkv -> LDS (keeps main loop's vmem queue = staging loads only)
#pragma unroll
  for (int i = 0; i < 6; ++i) BQ[i * 256 + tid] = bqkv[i * 256 + tid];

  // ---- x A-fragments
  short8 xf[32];
#pragma unroll
  for (int mt = 0; mt < 2; ++mt) {
    const float* xr = x + ((size_t)n * 64 + wm * 32 + mt * 16 + l15) * 512;
#pragma unroll
    for (int kk = 0; kk < 16; ++kk) {
      float4 a = *(const float4*)(xr + kk * 32 + g * 8);
      float4 c = *(const float4*)(xr + kk * 32 + g * 8 + 4);
      short8 s;
      s[0] = (short)f2bf(a.x); s[1] = (short)f2bf(a.y);
      s[2] = (short)f2bf(a.z); s[3] = (short)f2bf(a.w);
      s[4] = (short)f2bf(c.x); s[5] = (short)f2bf(c.y);
      s[6] = (short)f2bf(c.z); s[7] = (short)f2bf(c.w);
      xf[mt * 16 + kk] = s;
    }
  }
  float b2d[16];
#pragma unroll
  for (int nt = 0; nt < 4; ++nt)
#pragma unroll
    for (int r = 0; r < 4; ++r)
      b2d[nt * 4 + r] = bias2d[(mrow + r) * 64 + nt * 16 + l15];

  LGKM0; BARR();   // BQ visible

  // prologue: chunks 0,1 -> bufs 0,1
  stage16k(WS, wq, w, lane);
  stage16k(WS + 16384, wq + 16384, w, lane);

  int b = 0, cur = 0;
  for (int h = 0; h < 8; ++h) {
    float bq2[2], bk2[2], bv2[2];
#pragma unroll
    for (int nt = 0; nt < 2; ++nt) {
      int col = h * 64 + wn * 32 + nt * 16 + l15;
      bq2[nt] = BQ[col];
      bk2[nt] = BQ[512 + col];
      bv2[nt] = BQ[1024 + col];
    }
#pragma unroll
    for (int rg = 0; rg < 3; ++rg) {
      f32x4 acc[2][2] = {};
#pragma unroll
      for (int c = 0; c < 4; ++c) {
        int tgt = cur + 2; if (tgt >= 3) tgt -= 3;
        if (b + 2 < 96) {
          stage16k(WS + tgt * 16384, wq + (size_t)(b + 2) * 16384, w, lane);
          VMCNT8;
        } else if (b + 1 < 96) { VMCNT4; } else { VMCNT0; }
        BARR();
        const char* ws = WS + cur * 16384;
        PRIO1;
#pragma unroll
        for (int ks = 0; ks < 4; ++ks) {
#pragma unroll
          for (int nt = 0; nt < 2; ++nt) {
            int row = wn * 32 + nt * 16 + l15;
            int kg = ks * 4 + g;
            int us = (kg & 8) | ((kg ^ row) & 7);
            short8 bfr = *(const short8*)(ws + row * 256 + us * 16);
            acc[0][nt] = mfma16(xf[c * 4 + ks], bfr, acc[0][nt]);
            acc[1][nt] = mfma16(xf[16 + c * 4 + ks], bfr, acc[1][nt]);
          }
        }
        PRIO0;
        BARR();
        ++b; ++cur; if (cur >= 3) cur -= 3;
      }
      // writeback to swizzled scratch
      if (rg == 0) {
#pragma unroll
        for (int mt = 0; mt < 2; ++mt)
#pragma unroll
          for (int nt = 0; nt < 2; ++nt)
#pragma unroll
            for (int r = 0; r < 4; ++r)
              wr2s(B0, wm * 32 + mt * 16 + g * 4 + r, wn * 32 + nt * 16 + l15,
                   f2bf(acc[mt][nt][r] + bq2[nt]));
      } else if (rg == 1) {
#pragma unroll
        for (int mt = 0; mt < 2; ++mt)
#pragma unroll
          for (int nt = 0; nt < 2; ++nt)
#pragma unroll
            for (int r = 0; r < 4; ++r)
              wr2s(B1, wm * 32 + mt * 16 + g * 4 + r, wn * 32 + nt * 16 + l15,
                   f2bf(acc[mt][nt][r] + bk2[nt]));
      } else {  // V transposed: Vt[d][tok], 4 toks per uint2
#pragma unroll
        for (int mt = 0; mt < 2; ++mt)
#pragma unroll
          for (int nt = 0; nt < 2; ++nt) {
            unsigned short p0 = f2bf(acc[mt][nt][0] + bv2[nt]);
            unsigned short p1 = f2bf(acc[mt][nt][1] + bv2[nt]);
            unsigned short p2 = f2bf(acc[mt][nt][2] + bv2[nt]);
            unsigned short p3 = f2bf(acc[mt][nt][3] + bv2[nt]);
            unsigned lo = (unsigned)p0 | ((unsigned)p1 << 16);
            unsigned hi = (unsigned)p2 | ((unsigned)p3 << 16);
            wr8s(B2, wn * 32 + nt * 16 + l15, wm * 32 + mt * 16 + g * 4,
                 make_uint2(lo, hi));
          }
      }
    }
    LGKM0; BARR();   // Q/K/Vt visible to all waves

    // ---- scores + softmax: P -> B0 (wave-own rows)
    {
      f32x4 sc[4] = {};
      short8 aq0 = rd8s(B0, wrow, g);
      short8 aq1 = rd8s(B0, wrow, 4 + g);
#pragma unroll
      for (int nt = 0; nt < 4; ++nt)
        sc[nt] = mfma16(aq0, rd8s(B1, nt * 16 + l15, g), sc[nt]);
#pragma unroll
      for (int nt = 0; nt < 4; ++nt)
        sc[nt] = mfma16(aq1, rd8s(B1, nt * 16 + l15, 4 + g), sc[nt]);
      float mx[4] = {-1e30f, -1e30f, -1e30f, -1e30f};
#pragma unroll
      for (int nt = 0; nt < 4; ++nt)
#pragma unroll
        for (int r = 0; r < 4; ++r) {
          float v = sc[nt][r] * 0.125f + b2d[nt * 4 + r];
          sc[nt][r] = v;
          mx[r] = fmaxf(mx[r], v);
        }
#pragma unroll
      for (int mk = 1; mk < 16; mk <<= 1)
#pragma unroll
        for (int r = 0; r < 4; ++r) mx[r] = fmaxf(mx[r], __shfl_xor(mx[r], mk));
      float sm[4] = {0.f, 0.f, 0.f, 0.f};
#pragma unroll
      for (int nt = 0; nt < 4; ++nt)
#pragma unroll
        for (int r = 0; r < 4; ++r) {
          float e = __expf(sc[nt][r] - mx[r]);
          sc[nt][r] = e;
          sm[r] += e;
        }
#pragma unroll
      for (int mk = 1; mk < 16; mk <<= 1)
#pragma unroll
        for (int r = 0; r < 4; ++r) sm[r] += __shfl_xor(sm[r], mk);
      float inv[4];
#pragma unroll
      for (int r = 0; r < 4; ++r) inv[r] = 1.0f / sm[r];
#pragma unroll
      for (int nt = 0; nt < 4; ++nt)
#pragma unroll
        for (int r = 0; r < 4; ++r)
          wr2s(B0, mrow + r, nt * 16 + l15, f2bf(sc[nt][r] * inv[r]));
    }

    // ---- PV (P own rows in-wave; Vt stable since pre-scores barrier)
    f32x4 cv[4] = {};
    {
      short8 ap0 = rd8s(B0, wrow, g);
      short8 ap1 = rd8s(B0, wrow, 4 + g);
#pragma unroll
      for (int nt = 0; nt < 4; ++nt)
        cv[nt] = mfma16(ap0, rd8s(B2, nt * 16 + l15, g), cv[nt]);
#pragma unroll
      for (int nt = 0; nt < 4; ++nt)
        cv[nt] = mfma16(ap1, rd8s(B2, nt * 16 + l15, 4 + g), cv[nt]);
    }
    BARR();   // all waves' K reads (scores) complete before ctx overwrites B1
#pragma unroll
    for (int nt = 0; nt < 4; ++nt)
#pragma unroll
      for (int r = 0; r < 4; ++r)
        wr2s(B1, mrow + r, nt * 16 + l15, f2bf(cv[nt][r]));
    LGKM0; BARR();

    // ---- ctx copyout: contiguous 8KB/head, swizzle cancels (slot->slot)
    {
      char* cdst = ctxg + (size_t)n * 131072 + h * 8192;
#pragma unroll
      for (int it = 0; it < 2; ++it) {
        int flat = it * 256 + tid;
        int row = flat >> 3, s = flat & 7;
        uint4 v = *(const uint4*)(B1 + row * 128 + s * 16);
        *(uint4*)(cdst + row * 128 + s * 16) = v;
      }
    }
  }
}

// ============================ K3: oproj_ln =================================
__global__ __launch_bounds__(256)
__attribute__((amdgpu_waves_per_eu(2, 2))) void oproj_ln(
    const char* __restrict__ ctxg,      // 8KB/head ctx blocks in d_out
    const char* __restrict__ wo,        // 32 x 16KB Wo chunks
    const float* __restrict__ bo,
    const float* __restrict__ x,
    const float* __restrict__ lng,
    const float* __restrict__ lnb,
    float* __restrict__ out) {
  __shared__ __attribute__((aligned(16))) char smem[65536];
  char* WB = smem;            // 2 x 16KB Wo stage
  char* CB = smem + 32768;    // 2 x 16KB ctx stage (2 heads x 8KB each)
  float* EP  = (float*)smem;           // epilogue [64][68] f32 (overlays WB)
  float* SM1 = (float*)(smem + 32768); // [64][2] partials (overlays CB)
  float* SM2 = (float*)(smem + 33408);

  const int n = blockIdx.x;
  const int tid = threadIdx.x;
  const int w = tid >> 6, lane = tid & 63;
  const int l15 = lane & 15, g = lane >> 4;
  const int um = w >> 1, un = w & 1;

  const char* cbase = ctxg + (size_t)n * 131072;

  stage16k(CB, cbase, w, lane);
  stage16k(WB, wo, w, lane);

  f32x4 acc[8][2][2] = {};

  for (int kc = 0; kc < 4; ++kc) {
    short8 actx[2][4];
#pragma unroll
    for (int ng = 0; ng < 8; ++ng) {
      int b = kc * 8 + ng;
      if (b < 31)
        stage16k(WB + (((b + 1) & 1) << 14), wo + (size_t)(b + 1) * 16384, w, lane);
      if ((ng & 1) == 0 && kc < 3) {  // ctx piece (ng>>1) of chunk kc+1
        int p = ng >> 1;
        int off = p * 4096 + w * 1024;
        __builtin_amdgcn_global_load_lds(
            (const as1_u32*)(cbase + (kc + 1) * 16384 + off + lane * 16),
            (as3_u32*)(CB + (((kc + 1) & 1) << 14) + off), 16, 0, 0);
      }
      if (b < 31) { VMCNT5; } else { VMCNT0; }
      BARR();
      const char* cb = CB + ((kc & 1) << 14);
      if (ng == 0) {
#pragma unroll
        for (int mt = 0; mt < 2; ++mt)
#pragma unroll
          for (int ks = 0; ks < 4; ++ks) {
            int row = um * 32 + mt * 16 + l15;
            int u = ks * 4 + g;   // k-unit: head = u>>3, unit-in-head = u&7
            actx[mt][ks] = *(const short8*)(cb + (u >> 3) * 8192 + row * 128 +
                                            (((u & 7) ^ (row & 7)) * 16));
          }
      }
      const char* ws = WB + ((b & 1) << 14);
      PRIO1;
#pragma unroll
      for (int ks = 0; ks < 4; ++ks) {
#pragma unroll
        for (int nt = 0; nt < 2; ++nt) {
          int row = un * 32 + nt * 16 + l15;
          int kg = ks * 4 + g;
          int us = (kg & 8) | ((kg ^ row) & 7);
          short8 bfr = *(const short8*)(ws + row * 256 + us * 16);
          acc[ng][0][nt] = mfma16(actx[0][ks], bfr, acc[ng][0][nt]);
          acc[ng][1][nt] = mfma16(actx[1][ks], bfr, acc[ng][1][nt]);
        }
      }
      PRIO0;
      BARR();
    }
  }

  // ================= epilogue: +bo, +residual, LayerNorm ===================
  VMCNT0;
  const float* xblk = x + (size_t)n * 32768;
  float* oblk = out + (size_t)n * 32768;
  float s1[2][4] = {}, s2[2][4] = {};

#pragma unroll
  for (int ng = 0; ng < 8; ++ng) {
#pragma unroll
    for (int t = 0; t < 4; ++t) {
      int flat = t * 256 + tid;
      int row = flat >> 4, f4 = flat & 15;
      float4 v = *(const float4*)(xblk + row * 512 + ng * 64 + f4 * 4);
      *(float4*)(EP + row * 68 + f4 * 4) = v;
    }
    LGKM0; BARR();
    float boA[2];
#pragma unroll
    for (int nt = 0; nt < 2; ++nt) boA[nt] = bo[ng * 64 + un * 32 + nt * 16 + l15];
#pragma unroll
    for (int mt = 0; mt < 2; ++mt)
#pragma unroll
      for (int nt = 0; nt < 2; ++nt)
#pragma unroll
        for (int r = 0; r < 4; ++r) {
          int row = um * 32 + mt * 16 + g * 4 + r;
          float xv = EP[row * 68 + un * 32 + nt * 16 + l15];
          float v = acc[ng][mt][nt][r] + boA[nt] + xv;
          acc[ng][mt][nt][r] = v;
          s1[mt][r] += v;
          s2[mt][r] += v * v;
        }
    LGKM0; BARR();
  }
#pragma unroll
  for (int mk = 1; mk < 16; mk <<= 1)
#pragma unroll
    for (int mt = 0; mt < 2; ++mt)
#pragma unroll
      for (int r = 0; r < 4; ++r) {
        s1[mt][r] += __shfl_xor(s1[mt][r], mk);
        s2[mt][r] += __shfl_xor(s2[mt][r], mk);
      }
  if (l15 == 0) {
#pragma unroll
    for (int mt = 0; mt < 2; ++mt)
#pragma unroll
      for (int r = 0; r < 4; ++r) {
        int row = um * 32 + mt * 16 + g * 4 + r;
        SM1[row * 2 + un] = s1[mt][r];
        SM2[row * 2 + un] = s2[mt][r];
      }
  }
  LGKM0; BARR();
  float mu[2][4], rs[2][4];
#pragma unroll
  for (int mt = 0; mt < 2; ++mt)
#pragma unroll
    for (int r = 0; r < 4; ++r) {
      int row = um * 32 + mt * 16 + g * 4 + r;
      float a1 = SM1[row * 2] + SM1[row * 2 + 1];
      float a2 = SM2[row * 2] + SM2[row * 2 + 1];
      float m = a1 * (1.0f / 512.0f);
      float var = a2 * (1.0f / 512.0f) - m * m;
      mu[mt][r] = m;
      rs[mt][r] = rsqrtf(var + 1e-5f);
    }
  BARR();
#pragma unroll
  for (int ng = 0; ng < 8; ++ng) {
    float lgA[2], lbA[2];
#pragma unroll
    for (int nt = 0; nt < 2; ++nt) {
      int col = ng * 64 + un * 32 + nt * 16 + l15;
      lgA[nt] = lng[col];
      lbA[nt] = lnb[col];
    }
#pragma unroll
    for (int mt = 0; mt < 2; ++mt)
#pragma unroll
      for (int nt = 0; nt < 2; ++nt)
#pragma unroll
        for (int r = 0; r < 4; ++r) {
          int row = um * 32 + mt * 16 + g * 4 + r;
          EP[row * 68 + un * 32 + nt * 16 + l15] =
              (acc[ng][mt][nt][r] - mu[mt][r]) * rs[mt][r] * lgA[nt] + lbA[nt];
        }
    LGKM0; BARR();
#pragma unroll
    for (int t = 0; t < 4; ++t) {
      int flat = t * 256 + tid;
      int row = flat >> 4, f4 = flat & 15;
      *(float4*)(oblk + row * 512 + ng * 64 + f4 * 4) =
          *(const float4*)(EP + row * 68 + f4 * 4);
    }
    BARR();
  }
}

// ============================ launch =======================================
extern "C" void kernel_launch(void* const* d_in, const int* in_sizes, int n_in,
                              void* d_out, int out_size, void* d_ws, size_t ws_size,
                              hipStream_t stream) {
  const float* x    = (const float*)d_in[0];
  const float* wqkv = (const float*)d_in[1];
  const float* bqkv = (const float*)d_in[2];
  const float* wo   = (const float*)d_in[3];
  const float* bo   = (const float*)d_in[4];
  const float* lng  = (const float*)d_in[5];
  const float* lnb  = (const float*)d_in[6];
  const float* rel  = (const float*)d_in[7];

  // ws: 96 QKV chunks + 32 Wo chunks (16KB each) | bias2d f32 16KB
  unsigned short* wt = (unsigned short*)d_ws;
  float* bias2d = (float*)((char*)d_ws + 128 * 16384);
  const char* wqc = (const char*)d_ws;
  const char* woc = (const char*)d_ws + 96 * 16384;

  hipFuncSetAttribute(reinterpret_cast<const void*>(attn_qkv),
                      hipFuncAttributeMaxDynamicSharedMemorySize, 79872);

  prep_kernel<<<144, 256, 0, stream>>>(wqkv, wo, rel, wt, bias2d);
  attn_qkv<<<2048, 256, 79872, stream>>>(x, wqc, bqkv, bias2d, (char*)d_out);
  oproj_ln<<<2048, 256, 0, stream>>>((const char*)d_out, woc, bo, x, lng, lnb,
                                     (float*)d_out);
}